// Round 6
// baseline (194.904 us; speedup 1.0000x reference)
//
#include <hip/hip_runtime.h>
#include <math.h>

// Problem constants (match reference)
#define N_NODES 50000
#define N_EDGES 800000
#define DFEAT   128
#define MAXNORM (1.0f - 4e-3f)   // (1 - BALL_EPS)/sqrt(c), c=1
#define CAP     64               // padded adjacency slots per row (deg ~ Poisson(16), max ~45)
#define OVF_CAP 8192

// ==================== tier 1: bf16-staged padded path ====================

// Fused: zero deg/ovf_cnt + convert x (fp32) -> xb (bf16, RNE), 8 floats/thread.
__global__ __launch_bounds__(256) void k_prep(const float* __restrict__ x,
                                              unsigned int* __restrict__ xb,   // packed 2x bf16 per word
                                              int* __restrict__ deg,
                                              int* __restrict__ ovf_cnt, int nwords8) {
    int t = blockIdx.x * blockDim.x + threadIdx.x;
    if (t < N_NODES) deg[t] = 0;
    if (t == 0) *ovf_cnt = 0;
    if (t >= nwords8) return;
    const float4* x4 = (const float4*)x;
    float4 a = x4[2 * t];
    float4 b = x4[2 * t + 1];
    float fs[8] = {a.x, a.y, a.z, a.w, b.x, b.y, b.z, b.w};
    unsigned int w[4];
    #pragma unroll
    for (int k = 0; k < 4; ++k) {
        unsigned int lo = __float_as_uint(fs[2 * k]);
        unsigned int hi = __float_as_uint(fs[2 * k + 1]);
        lo = (lo + 0x7FFFu + ((lo >> 16) & 1u)) >> 16;          // RNE to bf16
        hi = (hi + 0x7FFFu + ((hi >> 16) & 1u)) >> 16;
        w[k] = lo | (hi << 16);
    }
    ((uint4*)xb)[t] = make_uint4(w[0], w[1], w[2], w[3]);
}

// one pass over edges: histogram + scatter into padded rows
__global__ void k_build(const int* __restrict__ row, const int* __restrict__ col,
                        int* __restrict__ deg, int* __restrict__ adj,
                        int* __restrict__ ovf, int* __restrict__ ovf_cnt, int e4) {
    int i = blockIdx.x * blockDim.x + threadIdx.x;
    if (i >= e4) return;
    int4 r4 = ((const int4*)row)[i];
    int4 c4 = ((const int4*)col)[i];
    int rs[4] = {r4.x, r4.y, r4.z, r4.w};
    int cs[4] = {c4.x, c4.y, c4.z, c4.w};
    #pragma unroll
    for (int k = 0; k < 4; ++k) {
        int r = rs[k], c = cs[k];
        if (r != c) {
            int pos = atomicAdd(&deg[r], 1);
            if (pos < CAP) adj[r * CAP + pos] = c;
            else {
                int o = atomicAdd(ovf_cnt, 1);
                if (o < OVF_CAP) { ovf[2 * o] = r; ovf[2 * o + 1] = c; }
            }
        }
    }
}

__device__ __forceinline__ float bf_lo(unsigned int w) { return __uint_as_float(w << 16); }
__device__ __forceinline__ float bf_hi(unsigned int w) { return __uint_as_float(w & 0xFFFF0000u); }

// One wave per destination row; each lane owns 2 features read as one bf16x2 word.
// Structure proven in r5; only the x-source (bf16 words) changed.
__global__ __launch_bounds__(256) void k_gather_bf(const unsigned int* __restrict__ xb,
                                                   const int* __restrict__ adj,
                                                   const int* __restrict__ deg,
                                                   const int* __restrict__ ovf,
                                                   const int* __restrict__ ovf_cnt,
                                                   float* __restrict__ out, int n) {
    int lane = threadIdx.x & 63;
    int rowi = blockIdx.x * 4 + (threadIdx.x >> 6);
    if (rowi >= n) return;

    int cnt    = deg[rowi];
    int capcnt = cnt < CAP ? cnt : CAP;

    int a = 0;
    if (lane < capcnt) a = adj[rowi * CAP + lane];   // one coalesced load per row

    float accx = 0.f, accy = 0.f;
    for (int nb = 0; nb < capcnt; ++nb) {
        int c = __shfl(a, nb);
        float w = rsqrtf((float)(deg[c] + 1));       // dis[col]
        unsigned int v = xb[c * (DFEAT / 2) + lane]; // 256B per wave per neighbor
        accx += w * bf_lo(v);
        accy += w * bf_hi(v);
    }

    // overflow edges (statistically never non-empty, kept for correctness)
    int novf = *ovf_cnt;
    for (int k = 0; k < novf; ++k) {
        if (ovf[2 * k] == rowi) {
            int c = ovf[2 * k + 1];
            float w = rsqrtf((float)(deg[c] + 1));
            unsigned int v = xb[c * (DFEAT / 2) + lane];
            accx += w * bf_lo(v);
            accy += w * bf_hi(v);
        }
    }

    float di = rsqrtf((float)(cnt + 1));             // dis[row]
    unsigned int sv = xb[rowi * (DFEAT / 2) + lane];
    // result = di * (sum + di * self)
    accx = di * (accx + di * bf_lo(sv));
    accy = di * (accy + di * bf_hi(sv));

    // 64-lane norm^2 reduction
    float nsq = accx * accx + accy * accy;
    #pragma unroll
    for (int off = 32; off > 0; off >>= 1) nsq += __shfl_xor(nsq, off);

    float un = fmaxf(sqrtf(nsq), 1e-15f);
    float th = tanhf(un);
    float scale = th / un;                           // expmap0
    if (th > MAXNORM) scale *= MAXNORM / th;         // proj clamp (||p|| == tanh(un))

    float2 o = make_float2(accx * scale, accy * scale);
    ((float2*)out)[rowi * (DFEAT / 2) + lane] = o;
}

// ==================== tier 2: fp32 padded path (proven round-5) ====================

__global__ void k_zero(int* __restrict__ deg, int* __restrict__ ovf_cnt, int n) {
    int i = blockIdx.x * blockDim.x + threadIdx.x;
    if (i < n) deg[i] = 0;
    if (i == 0) *ovf_cnt = 0;
}

__global__ __launch_bounds__(256) void k_gather_pad(const float* __restrict__ x,
                                                    const int* __restrict__ adj,
                                                    const int* __restrict__ deg,
                                                    const int* __restrict__ ovf,
                                                    const int* __restrict__ ovf_cnt,
                                                    float* __restrict__ out, int n) {
    int lane = threadIdx.x & 63;
    int rowi = blockIdx.x * 4 + (threadIdx.x >> 6);
    if (rowi >= n) return;

    const float2* __restrict__ x2 = (const float2*)x;
    int cnt    = deg[rowi];
    int capcnt = cnt < CAP ? cnt : CAP;

    int a = 0;
    if (lane < capcnt) a = adj[rowi * CAP + lane];

    float2 acc = make_float2(0.0f, 0.0f);
    for (int nb = 0; nb < capcnt; ++nb) {
        int c = __shfl(a, nb);
        float w = rsqrtf((float)(deg[c] + 1));
        float2 v = x2[c * (DFEAT / 2) + lane];
        acc.x += w * v.x;
        acc.y += w * v.y;
    }

    int novf = *ovf_cnt;
    for (int k = 0; k < novf; ++k) {
        if (ovf[2 * k] == rowi) {
            int c = ovf[2 * k + 1];
            float w = rsqrtf((float)(deg[c] + 1));
            float2 v = x2[c * (DFEAT / 2) + lane];
            acc.x += w * v.x;
            acc.y += w * v.y;
        }
    }

    float di = rsqrtf((float)(cnt + 1));
    float2 self = x2[rowi * (DFEAT / 2) + lane];
    acc.x = di * (acc.x + di * self.x);
    acc.y = di * (acc.y + di * self.y);

    float nsq = acc.x * acc.x + acc.y * acc.y;
    #pragma unroll
    for (int off = 32; off > 0; off >>= 1) nsq += __shfl_xor(nsq, off);

    float un = fmaxf(sqrtf(nsq), 1e-15f);
    float th = tanhf(un);
    float scale = th / un;
    if (th > MAXNORM) scale *= MAXNORM / th;

    float2 o = make_float2(acc.x * scale, acc.y * scale);
    ((float2*)out)[rowi * (DFEAT / 2) + lane] = o;
}

// ==================== tier 3: CSR fallback (proven round-2) ====================

#define SCAN_BLK 256
#define NUM_SCAN_BLOCKS ((N_NODES + SCAN_BLK - 1) / SCAN_BLK)

__global__ void k_init_deg(int* __restrict__ deg, int n) {
    int i = blockIdx.x * blockDim.x + threadIdx.x;
    if (i < n) deg[i] = 1;
}

__global__ void k_hist(const int* __restrict__ row, const int* __restrict__ col,
                       int* __restrict__ deg, int e) {
    int i = blockIdx.x * blockDim.x + threadIdx.x;
    if (i < e) {
        int r = row[i], c = col[i];
        if (r != c) atomicAdd(&deg[r], 1);
    }
}

__global__ __launch_bounds__(SCAN_BLK) void k_block_sums(const int* __restrict__ deg,
                                                         int* __restrict__ blockSums, int n) {
    __shared__ int s[SCAN_BLK];
    int t = threadIdx.x;
    int i = blockIdx.x * SCAN_BLK + t;
    s[t] = (i < n) ? (deg[i] - 1) : 0;
    __syncthreads();
    for (int off = SCAN_BLK / 2; off > 0; off >>= 1) {
        if (t < off) s[t] += s[t + off];
        __syncthreads();
    }
    if (t == 0) blockSums[blockIdx.x] = s[0];
}

__global__ __launch_bounds__(SCAN_BLK) void k_scan_blocks(const int* __restrict__ blockSums,
                                                          int* __restrict__ blockBase) {
    __shared__ int s[SCAN_BLK];
    int t = threadIdx.x;
    s[t] = (t < NUM_SCAN_BLOCKS) ? blockSums[t] : 0;
    __syncthreads();
    for (int off = 1; off < SCAN_BLK; off <<= 1) {
        int v = (t >= off) ? s[t - off] : 0;
        __syncthreads();
        s[t] += v;
        __syncthreads();
    }
    if (t < NUM_SCAN_BLOCKS) blockBase[t] = (t == 0) ? 0 : s[t - 1];
}

__global__ __launch_bounds__(SCAN_BLK) void k_block_scan(const int* __restrict__ deg,
                                                         const int* __restrict__ blockBase,
                                                         int* __restrict__ offs,
                                                         int* __restrict__ cursor, int n) {
    __shared__ int s[SCAN_BLK];
    int t = threadIdx.x;
    int i = blockIdx.x * SCAN_BLK + t;
    int cnt = (i < n) ? (deg[i] - 1) : 0;
    s[t] = cnt;
    __syncthreads();
    for (int off = 1; off < SCAN_BLK; off <<= 1) {
        int v = (t >= off) ? s[t - off] : 0;
        __syncthreads();
        s[t] += v;
        __syncthreads();
    }
    if (i < n) {
        int excl = s[t] - cnt + blockBase[blockIdx.x];
        offs[i]   = excl;
        cursor[i] = excl;
    }
}

__global__ void k_scatter(const int* __restrict__ row, const int* __restrict__ col,
                          int* __restrict__ cursor, int* __restrict__ adj, int e) {
    int i = blockIdx.x * blockDim.x + threadIdx.x;
    if (i < e) {
        int r = row[i], c = col[i];
        if (r != c) {
            int pos = atomicAdd(&cursor[r], 1);
            adj[pos] = c;
        }
    }
}

__global__ __launch_bounds__(256) void k_gather_csr(const float* __restrict__ x,
                                                    const int* __restrict__ adj,
                                                    const int* __restrict__ offs,
                                                    const int* __restrict__ deg,
                                                    float* __restrict__ out, int n) {
    int lane = threadIdx.x & 63;
    int rowi = blockIdx.x * 4 + (threadIdx.x >> 6);
    if (rowi >= n) return;

    const float2* __restrict__ x2 = (const float2*)x;
    int beg = offs[rowi];
    int cnt = deg[rowi] - 1;

    float2 acc = make_float2(0.0f, 0.0f);
    for (int base = 0; base < cnt; base += 64) {
        int m = cnt - base; if (m > 64) m = 64;
        int a = 0;
        if (lane < m) a = adj[beg + base + lane];
        for (int nb = 0; nb < m; ++nb) {
            int c = __shfl(a, nb);
            float w = rsqrtf((float)deg[c]);
            float2 v = x2[c * (DFEAT / 2) + lane];
            acc.x += w * v.x;
            acc.y += w * v.y;
        }
    }
    float di = rsqrtf((float)deg[rowi]);
    float2 self = x2[rowi * (DFEAT / 2) + lane];
    acc.x = di * (acc.x + di * self.x);
    acc.y = di * (acc.y + di * self.y);

    float nsq = acc.x * acc.x + acc.y * acc.y;
    #pragma unroll
    for (int off = 32; off > 0; off >>= 1) nsq += __shfl_xor(nsq, off);

    float un = fmaxf(sqrtf(nsq), 1e-15f);
    float th = tanhf(un);
    float scale = th / un;
    if (th > MAXNORM) scale *= MAXNORM / th;

    float2 o = make_float2(acc.x * scale, acc.y * scale);
    ((float2*)out)[rowi * (DFEAT / 2) + lane] = o;
}

// ==================== launcher ====================

extern "C" void kernel_launch(void* const* d_in, const int* in_sizes, int n_in,
                              void* d_out, int out_size, void* d_ws, size_t ws_size,
                              hipStream_t stream) {
    const float* x          = (const float*)d_in[0];
    const int*   edge_index = (const int*)d_in[1];
    const int*   row = edge_index;            // [E]
    const int*   col = edge_index + N_EDGES;  // [E]
    float* out = (float*)d_out;
    char*  ws  = (char*)d_ws;

    size_t sz_xb  = sizeof(unsigned short) * (size_t)N_NODES * DFEAT;  // 12.8 MB
    size_t sz_adj = sizeof(int) * (size_t)N_NODES * CAP;               // 12.8 MB
    size_t sz_deg = sizeof(int) * (size_t)N_NODES;
    size_t need_bf  = sz_xb + sz_adj + sz_deg + sizeof(int) * (1 + 2 * (size_t)OVF_CAP);
    size_t need_pad = sz_adj + sz_deg + sizeof(int) * (1 + 2 * (size_t)OVF_CAP);

    dim3 blk(256);
    if (ws_size >= need_bf) {
        size_t off = 0;
        unsigned int* xb = (unsigned int*)(ws + off); off += sz_xb;    // 16B-aligned
        int* adj     = (int*)(ws + off); off += sz_adj;
        int* deg     = (int*)(ws + off); off += sz_deg;
        int* ovf_cnt = (int*)(ws + off); off += sizeof(int);
        int* ovf     = (int*)(ws + off);

        int nwords8 = N_NODES * DFEAT / 8;   // 800000 threads, 8 floats each
        k_prep<<<dim3((nwords8 + 255) / 256), blk, 0, stream>>>(x, xb, deg, ovf_cnt, nwords8);
        k_build<<<dim3((N_EDGES / 4 + 255) / 256), blk, 0, stream>>>(row, col, deg, adj, ovf, ovf_cnt, N_EDGES / 4);
        k_gather_bf<<<dim3((N_NODES + 3) / 4), blk, 0, stream>>>(xb, adj, deg, ovf, ovf_cnt, out, N_NODES);
    } else if (ws_size >= need_pad) {
        size_t off = 0;
        int* adj     = (int*)(ws + off); off += sz_adj;
        int* deg     = (int*)(ws + off); off += sz_deg;
        int* ovf_cnt = (int*)(ws + off); off += sizeof(int);
        int* ovf     = (int*)(ws + off);

        k_zero<<<dim3((N_NODES + 255) / 256), blk, 0, stream>>>(deg, ovf_cnt, N_NODES);
        k_build<<<dim3((N_EDGES / 4 + 255) / 256), blk, 0, stream>>>(row, col, deg, adj, ovf, ovf_cnt, N_EDGES / 4);
        k_gather_pad<<<dim3((N_NODES + 3) / 4), blk, 0, stream>>>(x, adj, deg, ovf, ovf_cnt, out, N_NODES);
    } else {
        size_t off = 0;
        int* deg       = (int*)(ws + off); off += sizeof(int) * (size_t)N_NODES;
        int* offs      = (int*)(ws + off); off += sizeof(int) * (size_t)N_NODES;
        int* cursor    = (int*)(ws + off); off += sizeof(int) * (size_t)N_NODES;
        int* blockSums = (int*)(ws + off); off += sizeof(int) * (size_t)NUM_SCAN_BLOCKS;
        int* blockBase = (int*)(ws + off); off += sizeof(int) * (size_t)NUM_SCAN_BLOCKS;
        int* adj       = (int*)(ws + off);

        k_init_deg<<<dim3((N_NODES + 255) / 256), blk, 0, stream>>>(deg, N_NODES);
        k_hist<<<dim3((N_EDGES + 255) / 256), blk, 0, stream>>>(row, col, deg, N_EDGES);
        k_block_sums<<<dim3(NUM_SCAN_BLOCKS), dim3(SCAN_BLK), 0, stream>>>(deg, blockSums, N_NODES);
        k_scan_blocks<<<dim3(1), dim3(SCAN_BLK), 0, stream>>>(blockSums, blockBase);
        k_block_scan<<<dim3(NUM_SCAN_BLOCKS), dim3(SCAN_BLK), 0, stream>>>(deg, blockBase, offs, cursor, N_NODES);
        k_scatter<<<dim3((N_EDGES + 255) / 256), blk, 0, stream>>>(row, col, cursor, adj, N_EDGES);
        k_gather_csr<<<dim3((N_NODES + 3) / 4), blk, 0, stream>>>(x, adj, offs, deg, out, N_NODES);
    }
}

// Round 7
// 171.148 us; speedup vs baseline: 1.1388x; 1.1388x over previous
//
#include <hip/hip_runtime.h>
#include <math.h>

// Problem constants (match reference)
#define N_NODES 50000
#define N_EDGES 800000
#define DFEAT   128
#define MAXNORM (1.0f - 4e-3f)   // (1 - BALL_EPS)/sqrt(c), c=1
#define CAP     64               // padded adjacency slots per row (deg ~ Poisson(16), max ~45)
#define OVF_CAP 8192

// ==================== tier 1: pre-scaled bf16 padded path ====================

__global__ void k_zero(int* __restrict__ deg, int* __restrict__ ovf_cnt, int n) {
    int i = blockIdx.x * blockDim.x + threadIdx.x;
    if (i < n) deg[i] = 0;
    if (i == 0) *ovf_cnt = 0;
}

// one pass over edges: histogram + scatter into padded rows
__global__ void k_build(const int* __restrict__ row, const int* __restrict__ col,
                        int* __restrict__ deg, int* __restrict__ adj,
                        int* __restrict__ ovf, int* __restrict__ ovf_cnt, int e4) {
    int i = blockIdx.x * blockDim.x + threadIdx.x;
    if (i >= e4) return;
    int4 r4 = ((const int4*)row)[i];
    int4 c4 = ((const int4*)col)[i];
    int rs[4] = {r4.x, r4.y, r4.z, r4.w};
    int cs[4] = {c4.x, c4.y, c4.z, c4.w};
    #pragma unroll
    for (int k = 0; k < 4; ++k) {
        int r = rs[k], c = cs[k];
        if (r != c) {
            int pos = atomicAdd(&deg[r], 1);
            if (pos < CAP) adj[r * CAP + pos] = c;
            else {
                int o = atomicAdd(ovf_cnt, 1);
                if (o < OVF_CAP) { ovf[2 * o] = r; ovf[2 * o + 1] = c; }
            }
        }
    }
}

// After build: xb[node] = bf16(x[node] * rsqrt(deg[node]+1)); row N_NODES = zeros.
// 16 threads per row (8 floats each). First N_NODES threads also pad their adj
// row up to a multiple of 4 with the sentinel node N_NODES.
__global__ __launch_bounds__(256) void k_prep(const float* __restrict__ x,
                                              const int* __restrict__ deg,
                                              unsigned int* __restrict__ xb,   // packed 2x bf16 per word
                                              int* __restrict__ adj, int nthreads) {
    int t = blockIdx.x * blockDim.x + threadIdx.x;
    if (t >= nthreads) return;

    // adj padding (one thread per row)
    if (t < N_NODES) {
        int d = deg[t];
        int dcap = d < CAP ? d : CAP;
        int up = (dcap + 3) & ~3;
        for (int p = dcap; p < up; ++p) adj[t * CAP + p] = N_NODES;
    }

    int node = t >> 4;            // 16 threads per row
    int part = t & 15;            // which 8-float chunk
    unsigned int w[4];
    if (node < N_NODES) {
        float dis = rsqrtf((float)(deg[node] + 1));
        const float4* x4 = (const float4*)(x + (size_t)node * DFEAT + part * 8);
        float4 a = x4[0];
        float4 b = x4[1];
        float fs[8] = {a.x, a.y, a.z, a.w, b.x, b.y, b.z, b.w};
        #pragma unroll
        for (int k = 0; k < 4; ++k) {
            unsigned int lo = __float_as_uint(fs[2 * k] * dis);
            unsigned int hi = __float_as_uint(fs[2 * k + 1] * dis);
            lo = (lo + 0x7FFFu + ((lo >> 16) & 1u)) >> 16;          // RNE to bf16
            hi = (hi + 0x7FFFu + ((hi >> 16) & 1u)) >> 16;
            w[k] = lo | (hi << 16);
        }
    } else {
        w[0] = w[1] = w[2] = w[3] = 0u;   // sentinel row: zeros
    }
    ((uint4*)xb)[t] = make_uint4(w[0], w[1], w[2], w[3]);
}

__device__ __forceinline__ float bf_lo(unsigned int w) { return __uint_as_float(w << 16); }
__device__ __forceinline__ float bf_hi(unsigned int w) { return __uint_as_float(w & 0xFFFF0000u); }

// One wave per destination row. xb rows are pre-scaled by dis[src], so the
// inner loop is just: broadcast index -> load bf16x2 -> add. Unrolled x4 over
// sentinel-padded adjacency for 4 loads in flight.
__global__ __launch_bounds__(256) void k_gather_bf(const unsigned int* __restrict__ xb,
                                                   const int* __restrict__ adj,
                                                   const int* __restrict__ deg,
                                                   const int* __restrict__ ovf,
                                                   const int* __restrict__ ovf_cnt,
                                                   float* __restrict__ out, int n) {
    int lane = threadIdx.x & 63;
    int rowi = blockIdx.x * 4 + (threadIdx.x >> 6);
    if (rowi >= n) return;

    int cnt    = deg[rowi];
    int capcnt = cnt < CAP ? cnt : CAP;
    int capR   = (capcnt + 3) & ~3;                  // padded trip count

    int a = N_NODES;
    if (lane < capR) a = adj[rowi * CAP + lane];     // one coalesced load per row

    const unsigned int* __restrict__ xl = xb + lane; // per-lane column base

    float accx = 0.f, accy = 0.f;
    for (int nb = 0; nb < capR; nb += 4) {
        int c0 = __shfl(a, nb);
        int c1 = __shfl(a, nb + 1);
        int c2 = __shfl(a, nb + 2);
        int c3 = __shfl(a, nb + 3);
        unsigned int v0 = xl[c0 * (DFEAT / 2)];
        unsigned int v1 = xl[c1 * (DFEAT / 2)];
        unsigned int v2 = xl[c2 * (DFEAT / 2)];
        unsigned int v3 = xl[c3 * (DFEAT / 2)];
        accx += bf_lo(v0); accy += bf_hi(v0);
        accx += bf_lo(v1); accy += bf_hi(v1);
        accx += bf_lo(v2); accy += bf_hi(v2);
        accx += bf_lo(v3); accy += bf_hi(v3);
    }

    // overflow edges (statistically never non-empty, kept for correctness)
    int novf = *ovf_cnt;
    for (int k = 0; k < novf; ++k) {
        if (ovf[2 * k] == rowi) {
            unsigned int v = xl[ovf[2 * k + 1] * (DFEAT / 2)];
            accx += bf_lo(v); accy += bf_hi(v);
        }
    }

    float di = rsqrtf((float)(cnt + 1));             // dis[row]
    unsigned int sv = xl[rowi * (DFEAT / 2)];        // self (pre-scaled by dis[row])
    // result = dis[i] * (sum_c xb[c] + xb[i])
    accx = di * (accx + bf_lo(sv));
    accy = di * (accy + bf_hi(sv));

    // 64-lane norm^2 reduction
    float nsq = accx * accx + accy * accy;
    #pragma unroll
    for (int off = 32; off > 0; off >>= 1) nsq += __shfl_xor(nsq, off);

    float un = fmaxf(sqrtf(nsq), 1e-15f);
    float th = tanhf(un);
    float scale = th / un;                           // expmap0
    if (th > MAXNORM) scale *= MAXNORM / th;         // proj clamp (||p|| == tanh(un))

    float2 o = make_float2(accx * scale, accy * scale);
    ((float2*)out)[rowi * (DFEAT / 2) + lane] = o;
}

// ==================== tier 2: fp32 padded path (proven round-5) ====================

__global__ __launch_bounds__(256) void k_gather_pad(const float* __restrict__ x,
                                                    const int* __restrict__ adj,
                                                    const int* __restrict__ deg,
                                                    const int* __restrict__ ovf,
                                                    const int* __restrict__ ovf_cnt,
                                                    float* __restrict__ out, int n) {
    int lane = threadIdx.x & 63;
    int rowi = blockIdx.x * 4 + (threadIdx.x >> 6);
    if (rowi >= n) return;

    const float2* __restrict__ x2 = (const float2*)x;
    int cnt    = deg[rowi];
    int capcnt = cnt < CAP ? cnt : CAP;

    int a = 0;
    if (lane < capcnt) a = adj[rowi * CAP + lane];

    float2 acc = make_float2(0.0f, 0.0f);
    for (int nb = 0; nb < capcnt; ++nb) {
        int c = __shfl(a, nb);
        float w = rsqrtf((float)(deg[c] + 1));
        float2 v = x2[c * (DFEAT / 2) + lane];
        acc.x += w * v.x;
        acc.y += w * v.y;
    }

    int novf = *ovf_cnt;
    for (int k = 0; k < novf; ++k) {
        if (ovf[2 * k] == rowi) {
            int c = ovf[2 * k + 1];
            float w = rsqrtf((float)(deg[c] + 1));
            float2 v = x2[c * (DFEAT / 2) + lane];
            acc.x += w * v.x;
            acc.y += w * v.y;
        }
    }

    float di = rsqrtf((float)(cnt + 1));
    float2 self = x2[rowi * (DFEAT / 2) + lane];
    acc.x = di * (acc.x + di * self.x);
    acc.y = di * (acc.y + di * self.y);

    float nsq = acc.x * acc.x + acc.y * acc.y;
    #pragma unroll
    for (int off = 32; off > 0; off >>= 1) nsq += __shfl_xor(nsq, off);

    float un = fmaxf(sqrtf(nsq), 1e-15f);
    float th = tanhf(un);
    float scale = th / un;
    if (th > MAXNORM) scale *= MAXNORM / th;

    float2 o = make_float2(acc.x * scale, acc.y * scale);
    ((float2*)out)[rowi * (DFEAT / 2) + lane] = o;
}

// ==================== tier 3: CSR fallback (proven round-2) ====================

#define SCAN_BLK 256
#define NUM_SCAN_BLOCKS ((N_NODES + SCAN_BLK - 1) / SCAN_BLK)

__global__ void k_init_deg(int* __restrict__ deg, int n) {
    int i = blockIdx.x * blockDim.x + threadIdx.x;
    if (i < n) deg[i] = 1;
}

__global__ void k_hist(const int* __restrict__ row, const int* __restrict__ col,
                       int* __restrict__ deg, int e) {
    int i = blockIdx.x * blockDim.x + threadIdx.x;
    if (i < e) {
        int r = row[i], c = col[i];
        if (r != c) atomicAdd(&deg[r], 1);
    }
}

__global__ __launch_bounds__(SCAN_BLK) void k_block_sums(const int* __restrict__ deg,
                                                         int* __restrict__ blockSums, int n) {
    __shared__ int s[SCAN_BLK];
    int t = threadIdx.x;
    int i = blockIdx.x * SCAN_BLK + t;
    s[t] = (i < n) ? (deg[i] - 1) : 0;
    __syncthreads();
    for (int off = SCAN_BLK / 2; off > 0; off >>= 1) {
        if (t < off) s[t] += s[t + off];
        __syncthreads();
    }
    if (t == 0) blockSums[blockIdx.x] = s[0];
}

__global__ __launch_bounds__(SCAN_BLK) void k_scan_blocks(const int* __restrict__ blockSums,
                                                          int* __restrict__ blockBase) {
    __shared__ int s[SCAN_BLK];
    int t = threadIdx.x;
    s[t] = (t < NUM_SCAN_BLOCKS) ? blockSums[t] : 0;
    __syncthreads();
    for (int off = 1; off < SCAN_BLK; off <<= 1) {
        int v = (t >= off) ? s[t - off] : 0;
        __syncthreads();
        s[t] += v;
        __syncthreads();
    }
    if (t < NUM_SCAN_BLOCKS) blockBase[t] = (t == 0) ? 0 : s[t - 1];
}

__global__ __launch_bounds__(SCAN_BLK) void k_block_scan(const int* __restrict__ deg,
                                                         const int* __restrict__ blockBase,
                                                         int* __restrict__ offs,
                                                         int* __restrict__ cursor, int n) {
    __shared__ int s[SCAN_BLK];
    int t = threadIdx.x;
    int i = blockIdx.x * SCAN_BLK + t;
    int cnt = (i < n) ? (deg[i] - 1) : 0;
    s[t] = cnt;
    __syncthreads();
    for (int off = 1; off < SCAN_BLK; off <<= 1) {
        int v = (t >= off) ? s[t - off] : 0;
        __syncthreads();
        s[t] += v;
        __syncthreads();
    }
    if (i < n) {
        int excl = s[t] - cnt + blockBase[blockIdx.x];
        offs[i]   = excl;
        cursor[i] = excl;
    }
}

__global__ void k_scatter(const int* __restrict__ row, const int* __restrict__ col,
                          int* __restrict__ cursor, int* __restrict__ adj, int e) {
    int i = blockIdx.x * blockDim.x + threadIdx.x;
    if (i < e) {
        int r = row[i], c = col[i];
        if (r != c) {
            int pos = atomicAdd(&cursor[r], 1);
            adj[pos] = c;
        }
    }
}

__global__ __launch_bounds__(256) void k_gather_csr(const float* __restrict__ x,
                                                    const int* __restrict__ adj,
                                                    const int* __restrict__ offs,
                                                    const int* __restrict__ deg,
                                                    float* __restrict__ out, int n) {
    int lane = threadIdx.x & 63;
    int rowi = blockIdx.x * 4 + (threadIdx.x >> 6);
    if (rowi >= n) return;

    const float2* __restrict__ x2 = (const float2*)x;
    int beg = offs[rowi];
    int cnt = deg[rowi] - 1;

    float2 acc = make_float2(0.0f, 0.0f);
    for (int base = 0; base < cnt; base += 64) {
        int m = cnt - base; if (m > 64) m = 64;
        int a = 0;
        if (lane < m) a = adj[beg + base + lane];
        for (int nb = 0; nb < m; ++nb) {
            int c = __shfl(a, nb);
            float w = rsqrtf((float)deg[c]);
            float2 v = x2[c * (DFEAT / 2) + lane];
            acc.x += w * v.x;
            acc.y += w * v.y;
        }
    }
    float di = rsqrtf((float)deg[rowi]);
    float2 self = x2[rowi * (DFEAT / 2) + lane];
    acc.x = di * (acc.x + di * self.x);
    acc.y = di * (acc.y + di * self.y);

    float nsq = acc.x * acc.x + acc.y * acc.y;
    #pragma unroll
    for (int off = 32; off > 0; off >>= 1) nsq += __shfl_xor(nsq, off);

    float un = fmaxf(sqrtf(nsq), 1e-15f);
    float th = tanhf(un);
    float scale = th / un;
    if (th > MAXNORM) scale *= MAXNORM / th;

    float2 o = make_float2(acc.x * scale, acc.y * scale);
    ((float2*)out)[rowi * (DFEAT / 2) + lane] = o;
}

// ==================== launcher ====================

extern "C" void kernel_launch(void* const* d_in, const int* in_sizes, int n_in,
                              void* d_out, int out_size, void* d_ws, size_t ws_size,
                              hipStream_t stream) {
    const float* x          = (const float*)d_in[0];
    const int*   edge_index = (const int*)d_in[1];
    const int*   row = edge_index;            // [E]
    const int*   col = edge_index + N_EDGES;  // [E]
    float* out = (float*)d_out;
    char*  ws  = (char*)d_ws;

    size_t sz_xb  = sizeof(unsigned short) * (size_t)(N_NODES + 1) * DFEAT;  // +1 sentinel row
    size_t sz_adj = sizeof(int) * (size_t)N_NODES * CAP;
    size_t sz_deg = sizeof(int) * (size_t)N_NODES;
    size_t need_bf  = sz_xb + sz_adj + sz_deg + sizeof(int) * (1 + 2 * (size_t)OVF_CAP);
    size_t need_pad = sz_adj + sz_deg + sizeof(int) * (1 + 2 * (size_t)OVF_CAP);

    dim3 blk(256);
    if (ws_size >= need_bf) {
        size_t off = 0;
        unsigned int* xb = (unsigned int*)(ws + off); off += sz_xb;    // 16B-aligned
        int* adj     = (int*)(ws + off); off += sz_adj;
        int* deg     = (int*)(ws + off); off += sz_deg;
        int* ovf_cnt = (int*)(ws + off); off += sizeof(int);
        int* ovf     = (int*)(ws + off);

        int nprep = (N_NODES + 1) * (DFEAT / 8);   // 16 threads per row incl. sentinel
        k_zero<<<dim3((N_NODES + 255) / 256), blk, 0, stream>>>(deg, ovf_cnt, N_NODES);
        k_build<<<dim3((N_EDGES / 4 + 255) / 256), blk, 0, stream>>>(row, col, deg, adj, ovf, ovf_cnt, N_EDGES / 4);
        k_prep<<<dim3((nprep + 255) / 256), blk, 0, stream>>>(x, deg, xb, adj, nprep);
        k_gather_bf<<<dim3((N_NODES + 3) / 4), blk, 0, stream>>>(xb, adj, deg, ovf, ovf_cnt, out, N_NODES);
    } else if (ws_size >= need_pad) {
        size_t off = 0;
        int* adj     = (int*)(ws + off); off += sz_adj;
        int* deg     = (int*)(ws + off); off += sz_deg;
        int* ovf_cnt = (int*)(ws + off); off += sizeof(int);
        int* ovf     = (int*)(ws + off);

        k_zero<<<dim3((N_NODES + 255) / 256), blk, 0, stream>>>(deg, ovf_cnt, N_NODES);
        k_build<<<dim3((N_EDGES / 4 + 255) / 256), blk, 0, stream>>>(row, col, deg, adj, ovf, ovf_cnt, N_EDGES / 4);
        k_gather_pad<<<dim3((N_NODES + 3) / 4), blk, 0, stream>>>(x, adj, deg, ovf, ovf_cnt, out, N_NODES);
    } else {
        size_t off = 0;
        int* deg       = (int*)(ws + off); off += sizeof(int) * (size_t)N_NODES;
        int* offs      = (int*)(ws + off); off += sizeof(int) * (size_t)N_NODES;
        int* cursor    = (int*)(ws + off); off += sizeof(int) * (size_t)N_NODES;
        int* blockSums = (int*)(ws + off); off += sizeof(int) * (size_t)NUM_SCAN_BLOCKS;
        int* blockBase = (int*)(ws + off); off += sizeof(int) * (size_t)NUM_SCAN_BLOCKS;
        int* adj       = (int*)(ws + off);

        k_init_deg<<<dim3((N_NODES + 255) / 256), blk, 0, stream>>>(deg, N_NODES);
        k_hist<<<dim3((N_EDGES + 255) / 256), blk, 0, stream>>>(row, col, deg, N_EDGES);
        k_block_sums<<<dim3(NUM_SCAN_BLOCKS), dim3(SCAN_BLK), 0, stream>>>(deg, blockSums, N_NODES);
        k_scan_blocks<<<dim3(1), dim3(SCAN_BLK), 0, stream>>>(blockSums, blockBase);
        k_block_scan<<<dim3(NUM_SCAN_BLOCKS), dim3(SCAN_BLK), 0, stream>>>(deg, blockBase, offs, cursor, N_NODES);
        k_scatter<<<dim3((N_EDGES + 255) / 256), blk, 0, stream>>>(row, col, cursor, adj, N_EDGES);
        k_gather_csr<<<dim3((N_NODES + 3) / 4), blk, 0, stream>>>(x, adj, offs, deg, out, N_NODES);
    }
}

// Round 8
// 166.918 us; speedup vs baseline: 1.1677x; 1.0253x over previous
//
#include <hip/hip_runtime.h>
#include <math.h>

// Problem constants (match reference)
#define N_NODES 50000
#define N_EDGES 800000
#define DFEAT   128
#define MAXNORM (1.0f - 4e-3f)   // (1 - BALL_EPS)/sqrt(c), c=1
#define CAP     64               // padded adjacency slots per row (deg ~ Poisson(16), max ~45)
#define OVF_CAP 8192

// ==================== tier 1: pre-scaled bf16 padded path ====================

__global__ void k_zero(int* __restrict__ deg, int* __restrict__ ovf_cnt, int n) {
    int i = blockIdx.x * blockDim.x + threadIdx.x;
    if (i < n) deg[i] = 0;
    if (i == 0) *ovf_cnt = 0;
}

// one pass over edges: histogram + scatter into padded rows
__global__ void k_build(const int* __restrict__ row, const int* __restrict__ col,
                        int* __restrict__ deg, int* __restrict__ adj,
                        int* __restrict__ ovf, int* __restrict__ ovf_cnt, int e4) {
    int i = blockIdx.x * blockDim.x + threadIdx.x;
    if (i >= e4) return;
    int4 r4 = ((const int4*)row)[i];
    int4 c4 = ((const int4*)col)[i];
    int rs[4] = {r4.x, r4.y, r4.z, r4.w};
    int cs[4] = {c4.x, c4.y, c4.z, c4.w};
    #pragma unroll
    for (int k = 0; k < 4; ++k) {
        int r = rs[k], c = cs[k];
        if (r != c) {
            int pos = atomicAdd(&deg[r], 1);
            if (pos < CAP) adj[r * CAP + pos] = c;
            else {
                int o = atomicAdd(ovf_cnt, 1);
                if (o < OVF_CAP) { ovf[2 * o] = r; ovf[2 * o + 1] = c; }
            }
        }
    }
}

// After build: xb[node] = bf16(x[node] * rsqrt(deg[node]+1)); row N_NODES = zeros.
// 16 threads per row (8 floats each).
__global__ __launch_bounds__(256) void k_prep(const float* __restrict__ x,
                                              const int* __restrict__ deg,
                                              unsigned int* __restrict__ xb,   // packed 2x bf16 per word
                                              int nthreads) {
    int t = blockIdx.x * blockDim.x + threadIdx.x;
    if (t >= nthreads) return;

    int node = t >> 4;            // 16 threads per row
    int part = t & 15;            // which 8-float chunk
    unsigned int w[4];
    if (node < N_NODES) {
        float dis = rsqrtf((float)(deg[node] + 1));
        const float4* x4 = (const float4*)(x + (size_t)node * DFEAT + part * 8);
        float4 a = x4[0];
        float4 b = x4[1];
        float fs[8] = {a.x, a.y, a.z, a.w, b.x, b.y, b.z, b.w};
        #pragma unroll
        for (int k = 0; k < 4; ++k) {
            unsigned int lo = __float_as_uint(fs[2 * k] * dis);
            unsigned int hi = __float_as_uint(fs[2 * k + 1] * dis);
            lo = (lo + 0x7FFFu + ((lo >> 16) & 1u)) >> 16;          // RNE to bf16
            hi = (hi + 0x7FFFu + ((hi >> 16) & 1u)) >> 16;
            w[k] = lo | (hi << 16);
        }
    } else {
        w[0] = w[1] = w[2] = w[3] = 0u;   // sentinel row: zeros
    }
    ((uint4*)xb)[t] = make_uint4(w[0], w[1], w[2], w[3]);
}

__device__ __forceinline__ float bf_lo(unsigned int w) { return __uint_as_float(w << 16); }
__device__ __forceinline__ float bf_hi(unsigned int w) { return __uint_as_float(w & 0xFFFF0000u); }

// One wave per destination row. xb rows pre-scaled by dis[src]; sentinel row
// N_NODES is zeros. Each lane loads uint2 (4 bf16), so 32 lanes cover one
// 256B row: lanes 0-31 take neighbor nb+2j, lanes 32-63 take nb+2j+1 — one
// VMEM instruction per TWO neighbors. Unrolled x4 (8 neighbors/iter).
__global__ __launch_bounds__(256) void k_gather_bf(const unsigned int* __restrict__ xb,
                                                   const int* __restrict__ adj,
                                                   const int* __restrict__ deg,
                                                   const int* __restrict__ ovf,
                                                   const int* __restrict__ ovf_cnt,
                                                   float* __restrict__ out, int n) {
    int lane = threadIdx.x & 63;
    int half = lane >> 5;
    int fl   = lane & 31;
    int rowi = blockIdx.x * 4 + (threadIdx.x >> 6);
    if (rowi >= n) return;

    int cnt    = deg[rowi];
    int capcnt = cnt < CAP ? cnt : CAP;
    int capR   = (capcnt + 7) & ~7;                  // trip count, 8 neighbors/iter

    // adj value per lane; lanes >= capcnt hold the sentinel (zero xb row)
    int a = N_NODES;
    if (lane < capcnt) a = adj[rowi * CAP + lane];

    const unsigned int* __restrict__ xw = xb + 2 * fl;   // lane's word pair base

    float acc0 = 0.f, acc1 = 0.f, acc2 = 0.f, acc3 = 0.f;
    for (int nb = 0; nb < capR; nb += 8) {
        int c0 = __shfl(a, nb + 0 + half);
        int c1 = __shfl(a, nb + 2 + half);
        int c2 = __shfl(a, nb + 4 + half);
        int c3 = __shfl(a, nb + 6 + half);
        uint2 v0 = *(const uint2*)(xw + c0 * (DFEAT / 2));
        uint2 v1 = *(const uint2*)(xw + c1 * (DFEAT / 2));
        uint2 v2 = *(const uint2*)(xw + c2 * (DFEAT / 2));
        uint2 v3 = *(const uint2*)(xw + c3 * (DFEAT / 2));
        acc0 += bf_lo(v0.x); acc1 += bf_hi(v0.x); acc2 += bf_lo(v0.y); acc3 += bf_hi(v0.y);
        acc0 += bf_lo(v1.x); acc1 += bf_hi(v1.x); acc2 += bf_lo(v1.y); acc3 += bf_hi(v1.y);
        acc0 += bf_lo(v2.x); acc1 += bf_hi(v2.x); acc2 += bf_lo(v2.y); acc3 += bf_hi(v2.y);
        acc0 += bf_lo(v3.x); acc1 += bf_hi(v3.x); acc2 += bf_lo(v3.y); acc3 += bf_hi(v3.y);
    }

    // overflow edges (statistically never non-empty); lanes 0-31 only, pre-combine
    int novf = *ovf_cnt;
    if (novf > 0 && half == 0) {
        for (int k = 0; k < novf; ++k) {
            if (ovf[2 * k] == rowi) {
                uint2 v = *(const uint2*)(xw + ovf[2 * k + 1] * (DFEAT / 2));
                acc0 += bf_lo(v.x); acc1 += bf_hi(v.x);
                acc2 += bf_lo(v.y); acc3 += bf_hi(v.y);
            }
        }
    }

    // combine halves (afterwards both halves hold identical full sums)
    acc0 += __shfl_xor(acc0, 32);
    acc1 += __shfl_xor(acc1, 32);
    acc2 += __shfl_xor(acc2, 32);
    acc3 += __shfl_xor(acc3, 32);

    // self term: xb[rowi] pre-scaled by dis[rowi]
    uint2 sv = *(const uint2*)(xw + rowi * (DFEAT / 2));
    acc0 += bf_lo(sv.x); acc1 += bf_hi(sv.x);
    acc2 += bf_lo(sv.y); acc3 += bf_hi(sv.y);

    float di = rsqrtf((float)(cnt + 1));             // dis[row]
    acc0 *= di; acc1 *= di; acc2 *= di; acc3 *= di;

    // norm^2: reduce within each 32-half (halves identical)
    float nsq = acc0 * acc0 + acc1 * acc1 + acc2 * acc2 + acc3 * acc3;
    #pragma unroll
    for (int off = 16; off > 0; off >>= 1) nsq += __shfl_xor(nsq, off);

    float un = fmaxf(sqrtf(nsq), 1e-15f);
    float th = tanhf(un);
    float scale = th / un;                           // expmap0
    if (th > MAXNORM) scale *= MAXNORM / th;         // proj clamp (||p|| == tanh(un))

    if (half == 0) {
        float4 o = make_float4(acc0 * scale, acc1 * scale, acc2 * scale, acc3 * scale);
        *(float4*)(out + (size_t)rowi * DFEAT + 4 * fl) = o;
    }
}

// ==================== tier 2: fp32 padded path (proven round-5) ====================

__global__ __launch_bounds__(256) void k_gather_pad(const float* __restrict__ x,
                                                    const int* __restrict__ adj,
                                                    const int* __restrict__ deg,
                                                    const int* __restrict__ ovf,
                                                    const int* __restrict__ ovf_cnt,
                                                    float* __restrict__ out, int n) {
    int lane = threadIdx.x & 63;
    int rowi = blockIdx.x * 4 + (threadIdx.x >> 6);
    if (rowi >= n) return;

    const float2* __restrict__ x2 = (const float2*)x;
    int cnt    = deg[rowi];
    int capcnt = cnt < CAP ? cnt : CAP;

    int a = 0;
    if (lane < capcnt) a = adj[rowi * CAP + lane];

    float2 acc = make_float2(0.0f, 0.0f);
    for (int nb = 0; nb < capcnt; ++nb) {
        int c = __shfl(a, nb);
        float w = rsqrtf((float)(deg[c] + 1));
        float2 v = x2[c * (DFEAT / 2) + lane];
        acc.x += w * v.x;
        acc.y += w * v.y;
    }

    int novf = *ovf_cnt;
    for (int k = 0; k < novf; ++k) {
        if (ovf[2 * k] == rowi) {
            int c = ovf[2 * k + 1];
            float w = rsqrtf((float)(deg[c] + 1));
            float2 v = x2[c * (DFEAT / 2) + lane];
            acc.x += w * v.x;
            acc.y += w * v.y;
        }
    }

    float di = rsqrtf((float)(cnt + 1));
    float2 self = x2[rowi * (DFEAT / 2) + lane];
    acc.x = di * (acc.x + di * self.x);
    acc.y = di * (acc.y + di * self.y);

    float nsq = acc.x * acc.x + acc.y * acc.y;
    #pragma unroll
    for (int off = 32; off > 0; off >>= 1) nsq += __shfl_xor(nsq, off);

    float un = fmaxf(sqrtf(nsq), 1e-15f);
    float th = tanhf(un);
    float scale = th / un;
    if (th > MAXNORM) scale *= MAXNORM / th;

    float2 o = make_float2(acc.x * scale, acc.y * scale);
    ((float2*)out)[rowi * (DFEAT / 2) + lane] = o;
}

// ==================== tier 3: CSR fallback (proven round-2) ====================

#define SCAN_BLK 256
#define NUM_SCAN_BLOCKS ((N_NODES + SCAN_BLK - 1) / SCAN_BLK)

__global__ void k_init_deg(int* __restrict__ deg, int n) {
    int i = blockIdx.x * blockDim.x + threadIdx.x;
    if (i < n) deg[i] = 1;
}

__global__ void k_hist(const int* __restrict__ row, const int* __restrict__ col,
                       int* __restrict__ deg, int e) {
    int i = blockIdx.x * blockDim.x + threadIdx.x;
    if (i < e) {
        int r = row[i], c = col[i];
        if (r != c) atomicAdd(&deg[r], 1);
    }
}

__global__ __launch_bounds__(SCAN_BLK) void k_block_sums(const int* __restrict__ deg,
                                                         int* __restrict__ blockSums, int n) {
    __shared__ int s[SCAN_BLK];
    int t = threadIdx.x;
    int i = blockIdx.x * SCAN_BLK + t;
    s[t] = (i < n) ? (deg[i] - 1) : 0;
    __syncthreads();
    for (int off = SCAN_BLK / 2; off > 0; off >>= 1) {
        if (t < off) s[t] += s[t + off];
        __syncthreads();
    }
    if (t == 0) blockSums[blockIdx.x] = s[0];
}

__global__ __launch_bounds__(SCAN_BLK) void k_scan_blocks(const int* __restrict__ blockSums,
                                                          int* __restrict__ blockBase) {
    __shared__ int s[SCAN_BLK];
    int t = threadIdx.x;
    s[t] = (t < NUM_SCAN_BLOCKS) ? blockSums[t] : 0;
    __syncthreads();
    for (int off = 1; off < SCAN_BLK; off <<= 1) {
        int v = (t >= off) ? s[t - off] : 0;
        __syncthreads();
        s[t] += v;
        __syncthreads();
    }
    if (t < NUM_SCAN_BLOCKS) blockBase[t] = (t == 0) ? 0 : s[t - 1];
}

__global__ __launch_bounds__(SCAN_BLK) void k_block_scan(const int* __restrict__ deg,
                                                         const int* __restrict__ blockBase,
                                                         int* __restrict__ offs,
                                                         int* __restrict__ cursor, int n) {
    __shared__ int s[SCAN_BLK];
    int t = threadIdx.x;
    int i = blockIdx.x * SCAN_BLK + t;
    int cnt = (i < n) ? (deg[i] - 1) : 0;
    s[t] = cnt;
    __syncthreads();
    for (int off = 1; off < SCAN_BLK; off <<= 1) {
        int v = (t >= off) ? s[t - off] : 0;
        __syncthreads();
        s[t] += v;
        __syncthreads();
    }
    if (i < n) {
        int excl = s[t] - cnt + blockBase[blockIdx.x];
        offs[i]   = excl;
        cursor[i] = excl;
    }
}

__global__ void k_scatter(const int* __restrict__ row, const int* __restrict__ col,
                          int* __restrict__ cursor, int* __restrict__ adj, int e) {
    int i = blockIdx.x * blockDim.x + threadIdx.x;
    if (i < e) {
        int r = row[i], c = col[i];
        if (r != c) {
            int pos = atomicAdd(&cursor[r], 1);
            adj[pos] = c;
        }
    }
}

__global__ __launch_bounds__(256) void k_gather_csr(const float* __restrict__ x,
                                                    const int* __restrict__ adj,
                                                    const int* __restrict__ offs,
                                                    const int* __restrict__ deg,
                                                    float* __restrict__ out, int n) {
    int lane = threadIdx.x & 63;
    int rowi = blockIdx.x * 4 + (threadIdx.x >> 6);
    if (rowi >= n) return;

    const float2* __restrict__ x2 = (const float2*)x;
    int beg = offs[rowi];
    int cnt = deg[rowi] - 1;

    float2 acc = make_float2(0.0f, 0.0f);
    for (int base = 0; base < cnt; base += 64) {
        int m = cnt - base; if (m > 64) m = 64;
        int a = 0;
        if (lane < m) a = adj[beg + base + lane];
        for (int nb = 0; nb < m; ++nb) {
            int c = __shfl(a, nb);
            float w = rsqrtf((float)deg[c]);
            float2 v = x2[c * (DFEAT / 2) + lane];
            acc.x += w * v.x;
            acc.y += w * v.y;
        }
    }
    float di = rsqrtf((float)deg[rowi]);
    float2 self = x2[rowi * (DFEAT / 2) + lane];
    acc.x = di * (acc.x + di * self.x);
    acc.y = di * (acc.y + di * self.y);

    float nsq = acc.x * acc.x + acc.y * acc.y;
    #pragma unroll
    for (int off = 32; off > 0; off >>= 1) nsq += __shfl_xor(nsq, off);

    float un = fmaxf(sqrtf(nsq), 1e-15f);
    float th = tanhf(un);
    float scale = th / un;
    if (th > MAXNORM) scale *= MAXNORM / th;

    float2 o = make_float2(acc.x * scale, acc.y * scale);
    ((float2*)out)[rowi * (DFEAT / 2) + lane] = o;
}

// ==================== launcher ====================

extern "C" void kernel_launch(void* const* d_in, const int* in_sizes, int n_in,
                              void* d_out, int out_size, void* d_ws, size_t ws_size,
                              hipStream_t stream) {
    const float* x          = (const float*)d_in[0];
    const int*   edge_index = (const int*)d_in[1];
    const int*   row = edge_index;            // [E]
    const int*   col = edge_index + N_EDGES;  // [E]
    float* out = (float*)d_out;
    char*  ws  = (char*)d_ws;

    size_t sz_xb  = sizeof(unsigned short) * (size_t)(N_NODES + 1) * DFEAT;  // +1 sentinel row
    size_t sz_adj = sizeof(int) * (size_t)N_NODES * CAP;
    size_t sz_deg = sizeof(int) * (size_t)N_NODES;
    size_t need_bf  = sz_xb + sz_adj + sz_deg + sizeof(int) * (1 + 2 * (size_t)OVF_CAP);
    size_t need_pad = sz_adj + sz_deg + sizeof(int) * (1 + 2 * (size_t)OVF_CAP);

    dim3 blk(256);
    if (ws_size >= need_bf) {
        size_t off = 0;
        unsigned int* xb = (unsigned int*)(ws + off); off += sz_xb;    // 16B-aligned
        int* adj     = (int*)(ws + off); off += sz_adj;
        int* deg     = (int*)(ws + off); off += sz_deg;
        int* ovf_cnt = (int*)(ws + off); off += sizeof(int);
        int* ovf     = (int*)(ws + off);

        int nprep = (N_NODES + 1) * (DFEAT / 8);   // 16 threads per row incl. sentinel
        k_zero<<<dim3((N_NODES + 255) / 256), blk, 0, stream>>>(deg, ovf_cnt, N_NODES);
        k_build<<<dim3((N_EDGES / 4 + 255) / 256), blk, 0, stream>>>(row, col, deg, adj, ovf, ovf_cnt, N_EDGES / 4);
        k_prep<<<dim3((nprep + 255) / 256), blk, 0, stream>>>(x, deg, xb, nprep);
        k_gather_bf<<<dim3((N_NODES + 3) / 4), blk, 0, stream>>>(xb, adj, deg, ovf, ovf_cnt, out, N_NODES);
    } else if (ws_size >= need_pad) {
        size_t off = 0;
        int* adj     = (int*)(ws + off); off += sz_adj;
        int* deg     = (int*)(ws + off); off += sz_deg;
        int* ovf_cnt = (int*)(ws + off); off += sizeof(int);
        int* ovf     = (int*)(ws + off);

        k_zero<<<dim3((N_NODES + 255) / 256), blk, 0, stream>>>(deg, ovf_cnt, N_NODES);
        k_build<<<dim3((N_EDGES / 4 + 255) / 256), blk, 0, stream>>>(row, col, deg, adj, ovf, ovf_cnt, N_EDGES / 4);
        k_gather_pad<<<dim3((N_NODES + 3) / 4), blk, 0, stream>>>(x, adj, deg, ovf, ovf_cnt, out, N_NODES);
    } else {
        size_t off = 0;
        int* deg       = (int*)(ws + off); off += sizeof(int) * (size_t)N_NODES;
        int* offs      = (int*)(ws + off); off += sizeof(int) * (size_t)N_NODES;
        int* cursor    = (int*)(ws + off); off += sizeof(int) * (size_t)N_NODES;
        int* blockSums = (int*)(ws + off); off += sizeof(int) * (size_t)NUM_SCAN_BLOCKS;
        int* blockBase = (int*)(ws + off); off += sizeof(int) * (size_t)NUM_SCAN_BLOCKS;
        int* adj       = (int*)(ws + off);

        k_init_deg<<<dim3((N_NODES + 255) / 256), blk, 0, stream>>>(deg, N_NODES);
        k_hist<<<dim3((N_EDGES + 255) / 256), blk, 0, stream>>>(row, col, deg, N_EDGES);
        k_block_sums<<<dim3(NUM_SCAN_BLOCKS), dim3(SCAN_BLK), 0, stream>>>(deg, blockSums, N_NODES);
        k_scan_blocks<<<dim3(1), dim3(SCAN_BLK), 0, stream>>>(blockSums, blockBase);
        k_block_scan<<<dim3(NUM_SCAN_BLOCKS), dim3(SCAN_BLK), 0, stream>>>(deg, blockBase, offs, cursor, N_NODES);
        k_scatter<<<dim3((N_EDGES + 255) / 256), blk, 0, stream>>>(row, col, cursor, adj, N_EDGES);
        k_gather_csr<<<dim3((N_NODES + 3) / 4), blk, 0, stream>>>(x, adj, offs, deg, out, N_NODES);
    }
}

// Round 9
// 160.101 us; speedup vs baseline: 1.2174x; 1.0426x over previous
//
#include <hip/hip_runtime.h>
#include <math.h>

// Problem constants (match reference)
#define N_NODES 50000
#define N_EDGES 800000
#define DFEAT   128
#define MAXNORM (1.0f - 4e-3f)   // (1 - BALL_EPS)/sqrt(c), c=1
#define CAP     64               // padded adjacency slots per row (deg ~ Poisson(16), max ~45)
#define OVF_CAP 8192

// ==================== tier 1: pre-scaled bf16 padded path ====================

__global__ void k_zero(int* __restrict__ deg, int* __restrict__ ovf_cnt, int n) {
    int i = blockIdx.x * blockDim.x + threadIdx.x;
    if (i < n) deg[i] = 0;
    if (i == 0) *ovf_cnt = 0;
}

// one pass over edges: histogram + scatter into padded rows.
// ONE EDGE PER THREAD: 12.5k waves saturate the 32-waves/CU capacity so the
// far-atomic latency is hidden by TLP (r8: 4 edges/thread = 28% occupancy,
// VALUBusy 0.3% -> pure vmcnt stall).
__global__ void k_build(const int* __restrict__ row, const int* __restrict__ col,
                        int* __restrict__ deg, int* __restrict__ adj,
                        int* __restrict__ ovf, int* __restrict__ ovf_cnt, int e) {
    int i = blockIdx.x * blockDim.x + threadIdx.x;
    if (i >= e) return;
    int r = row[i], c = col[i];
    if (r != c) {
        int pos = atomicAdd(&deg[r], 1);
        if (pos < CAP) adj[r * CAP + pos] = c;
        else {
            int o = atomicAdd(ovf_cnt, 1);
            if (o < OVF_CAP) { ovf[2 * o] = r; ovf[2 * o + 1] = c; }
        }
    }
}

// After build: xb[node] = bf16(x[node] * rsqrt(deg[node]+1)); row N_NODES = zeros.
// 16 threads per row (8 floats each).
__global__ __launch_bounds__(256) void k_prep(const float* __restrict__ x,
                                              const int* __restrict__ deg,
                                              unsigned int* __restrict__ xb,   // packed 2x bf16 per word
                                              int nthreads) {
    int t = blockIdx.x * blockDim.x + threadIdx.x;
    if (t >= nthreads) return;

    int node = t >> 4;            // 16 threads per row
    int part = t & 15;            // which 8-float chunk
    unsigned int w[4];
    if (node < N_NODES) {
        float dis = rsqrtf((float)(deg[node] + 1));
        const float4* x4 = (const float4*)(x + (size_t)node * DFEAT + part * 8);
        float4 a = x4[0];
        float4 b = x4[1];
        float fs[8] = {a.x, a.y, a.z, a.w, b.x, b.y, b.z, b.w};
        #pragma unroll
        for (int k = 0; k < 4; ++k) {
            unsigned int lo = __float_as_uint(fs[2 * k] * dis);
            unsigned int hi = __float_as_uint(fs[2 * k + 1] * dis);
            lo = (lo + 0x7FFFu + ((lo >> 16) & 1u)) >> 16;          // RNE to bf16
            hi = (hi + 0x7FFFu + ((hi >> 16) & 1u)) >> 16;
            w[k] = lo | (hi << 16);
        }
    } else {
        w[0] = w[1] = w[2] = w[3] = 0u;   // sentinel row: zeros
    }
    ((uint4*)xb)[t] = make_uint4(w[0], w[1], w[2], w[3]);
}

__device__ __forceinline__ float bf_lo(unsigned int w) { return __uint_as_float(w << 16); }
__device__ __forceinline__ float bf_hi(unsigned int w) { return __uint_as_float(w & 0xFFFF0000u); }

// One wave per destination row. xb rows pre-scaled by dis[src]; sentinel row
// N_NODES is zeros. Each lane loads uint2 (4 bf16), so 32 lanes cover one
// 256B row: lanes 0-31 take neighbor nb+2j, lanes 32-63 take nb+2j+1 — one
// VMEM instruction per TWO neighbors. Unrolled x4 (8 neighbors/iter).
__global__ __launch_bounds__(256) void k_gather_bf(const unsigned int* __restrict__ xb,
                                                   const int* __restrict__ adj,
                                                   const int* __restrict__ deg,
                                                   const int* __restrict__ ovf,
                                                   const int* __restrict__ ovf_cnt,
                                                   float* __restrict__ out, int n) {
    int lane = threadIdx.x & 63;
    int half = lane >> 5;
    int fl   = lane & 31;
    int rowi = blockIdx.x * 4 + (threadIdx.x >> 6);
    if (rowi >= n) return;

    int cnt    = deg[rowi];
    int capcnt = cnt < CAP ? cnt : CAP;
    int capR   = (capcnt + 7) & ~7;                  // trip count, 8 neighbors/iter

    // adj value per lane; lanes >= capcnt hold the sentinel (zero xb row)
    int a = N_NODES;
    if (lane < capcnt) a = adj[rowi * CAP + lane];

    const unsigned int* __restrict__ xw = xb + 2 * fl;   // lane's word pair base

    float acc0 = 0.f, acc1 = 0.f, acc2 = 0.f, acc3 = 0.f;
    for (int nb = 0; nb < capR; nb += 8) {
        int c0 = __shfl(a, nb + 0 + half);
        int c1 = __shfl(a, nb + 2 + half);
        int c2 = __shfl(a, nb + 4 + half);
        int c3 = __shfl(a, nb + 6 + half);
        uint2 v0 = *(const uint2*)(xw + c0 * (DFEAT / 2));
        uint2 v1 = *(const uint2*)(xw + c1 * (DFEAT / 2));
        uint2 v2 = *(const uint2*)(xw + c2 * (DFEAT / 2));
        uint2 v3 = *(const uint2*)(xw + c3 * (DFEAT / 2));
        acc0 += bf_lo(v0.x); acc1 += bf_hi(v0.x); acc2 += bf_lo(v0.y); acc3 += bf_hi(v0.y);
        acc0 += bf_lo(v1.x); acc1 += bf_hi(v1.x); acc2 += bf_lo(v1.y); acc3 += bf_hi(v1.y);
        acc0 += bf_lo(v2.x); acc1 += bf_hi(v2.x); acc2 += bf_lo(v2.y); acc3 += bf_hi(v2.y);
        acc0 += bf_lo(v3.x); acc1 += bf_hi(v3.x); acc2 += bf_lo(v3.y); acc3 += bf_hi(v3.y);
    }

    // overflow edges (statistically never non-empty); lanes 0-31 only, pre-combine
    int novf = *ovf_cnt;
    if (novf > 0 && half == 0) {
        for (int k = 0; k < novf; ++k) {
            if (ovf[2 * k] == rowi) {
                uint2 v = *(const uint2*)(xw + ovf[2 * k + 1] * (DFEAT / 2));
                acc0 += bf_lo(v.x); acc1 += bf_hi(v.x);
                acc2 += bf_lo(v.y); acc3 += bf_hi(v.y);
            }
        }
    }

    // combine halves (afterwards both halves hold identical full sums)
    acc0 += __shfl_xor(acc0, 32);
    acc1 += __shfl_xor(acc1, 32);
    acc2 += __shfl_xor(acc2, 32);
    acc3 += __shfl_xor(acc3, 32);

    // self term: xb[rowi] pre-scaled by dis[rowi]
    uint2 sv = *(const uint2*)(xw + rowi * (DFEAT / 2));
    acc0 += bf_lo(sv.x); acc1 += bf_hi(sv.x);
    acc2 += bf_lo(sv.y); acc3 += bf_hi(sv.y);

    float di = rsqrtf((float)(cnt + 1));             // dis[row]
    acc0 *= di; acc1 *= di; acc2 *= di; acc3 *= di;

    // norm^2: reduce within each 32-half (halves identical)
    float nsq = acc0 * acc0 + acc1 * acc1 + acc2 * acc2 + acc3 * acc3;
    #pragma unroll
    for (int off = 16; off > 0; off >>= 1) nsq += __shfl_xor(nsq, off);

    float un = fmaxf(sqrtf(nsq), 1e-15f);
    float th = tanhf(un);
    float scale = th / un;                           // expmap0
    if (th > MAXNORM) scale *= MAXNORM / th;         // proj clamp (||p|| == tanh(un))

    if (half == 0) {
        float4 o = make_float4(acc0 * scale, acc1 * scale, acc2 * scale, acc3 * scale);
        *(float4*)(out + (size_t)rowi * DFEAT + 4 * fl) = o;
    }
}

// ==================== tier 2: fp32 padded path (proven round-5) ====================

__global__ __launch_bounds__(256) void k_gather_pad(const float* __restrict__ x,
                                                    const int* __restrict__ adj,
                                                    const int* __restrict__ deg,
                                                    const int* __restrict__ ovf,
                                                    const int* __restrict__ ovf_cnt,
                                                    float* __restrict__ out, int n) {
    int lane = threadIdx.x & 63;
    int rowi = blockIdx.x * 4 + (threadIdx.x >> 6);
    if (rowi >= n) return;

    const float2* __restrict__ x2 = (const float2*)x;
    int cnt    = deg[rowi];
    int capcnt = cnt < CAP ? cnt : CAP;

    int a = 0;
    if (lane < capcnt) a = adj[rowi * CAP + lane];

    float2 acc = make_float2(0.0f, 0.0f);
    for (int nb = 0; nb < capcnt; ++nb) {
        int c = __shfl(a, nb);
        float w = rsqrtf((float)(deg[c] + 1));
        float2 v = x2[c * (DFEAT / 2) + lane];
        acc.x += w * v.x;
        acc.y += w * v.y;
    }

    int novf = *ovf_cnt;
    for (int k = 0; k < novf; ++k) {
        if (ovf[2 * k] == rowi) {
            int c = ovf[2 * k + 1];
            float w = rsqrtf((float)(deg[c] + 1));
            float2 v = x2[c * (DFEAT / 2) + lane];
            acc.x += w * v.x;
            acc.y += w * v.y;
        }
    }

    float di = rsqrtf((float)(cnt + 1));
    float2 self = x2[rowi * (DFEAT / 2) + lane];
    acc.x = di * (acc.x + di * self.x);
    acc.y = di * (acc.y + di * self.y);

    float nsq = acc.x * acc.x + acc.y * acc.y;
    #pragma unroll
    for (int off = 32; off > 0; off >>= 1) nsq += __shfl_xor(nsq, off);

    float un = fmaxf(sqrtf(nsq), 1e-15f);
    float th = tanhf(un);
    float scale = th / un;
    if (th > MAXNORM) scale *= MAXNORM / th;

    float2 o = make_float2(acc.x * scale, acc.y * scale);
    ((float2*)out)[rowi * (DFEAT / 2) + lane] = o;
}

// ==================== tier 3: CSR fallback (proven round-2) ====================

#define SCAN_BLK 256
#define NUM_SCAN_BLOCKS ((N_NODES + SCAN_BLK - 1) / SCAN_BLK)

__global__ void k_init_deg(int* __restrict__ deg, int n) {
    int i = blockIdx.x * blockDim.x + threadIdx.x;
    if (i < n) deg[i] = 1;
}

__global__ void k_hist(const int* __restrict__ row, const int* __restrict__ col,
                       int* __restrict__ deg, int e) {
    int i = blockIdx.x * blockDim.x + threadIdx.x;
    if (i < e) {
        int r = row[i], c = col[i];
        if (r != c) atomicAdd(&deg[r], 1);
    }
}

__global__ __launch_bounds__(SCAN_BLK) void k_block_sums(const int* __restrict__ deg,
                                                         int* __restrict__ blockSums, int n) {
    __shared__ int s[SCAN_BLK];
    int t = threadIdx.x;
    int i = blockIdx.x * SCAN_BLK + t;
    s[t] = (i < n) ? (deg[i] - 1) : 0;
    __syncthreads();
    for (int off = SCAN_BLK / 2; off > 0; off >>= 1) {
        if (t < off) s[t] += s[t + off];
        __syncthreads();
    }
    if (t == 0) blockSums[blockIdx.x] = s[0];
}

__global__ __launch_bounds__(SCAN_BLK) void k_scan_blocks(const int* __restrict__ blockSums,
                                                          int* __restrict__ blockBase) {
    __shared__ int s[SCAN_BLK];
    int t = threadIdx.x;
    s[t] = (t < NUM_SCAN_BLOCKS) ? blockSums[t] : 0;
    __syncthreads();
    for (int off = 1; off < SCAN_BLK; off <<= 1) {
        int v = (t >= off) ? s[t - off] : 0;
        __syncthreads();
        s[t] += v;
        __syncthreads();
    }
    if (t < NUM_SCAN_BLOCKS) blockBase[t] = (t == 0) ? 0 : s[t - 1];
}

__global__ __launch_bounds__(SCAN_BLK) void k_block_scan(const int* __restrict__ deg,
                                                         const int* __restrict__ blockBase,
                                                         int* __restrict__ offs,
                                                         int* __restrict__ cursor, int n) {
    __shared__ int s[SCAN_BLK];
    int t = threadIdx.x;
    int i = blockIdx.x * SCAN_BLK + t;
    int cnt = (i < n) ? (deg[i] - 1) : 0;
    s[t] = cnt;
    __syncthreads();
    for (int off = 1; off < SCAN_BLK; off <<= 1) {
        int v = (t >= off) ? s[t - off] : 0;
        __syncthreads();
        s[t] += v;
        __syncthreads();
    }
    if (i < n) {
        int excl = s[t] - cnt + blockBase[blockIdx.x];
        offs[i]   = excl;
        cursor[i] = excl;
    }
}

__global__ void k_scatter(const int* __restrict__ row, const int* __restrict__ col,
                          int* __restrict__ cursor, int* __restrict__ adj, int e) {
    int i = blockIdx.x * blockDim.x + threadIdx.x;
    if (i < e) {
        int r = row[i], c = col[i];
        if (r != c) {
            int pos = atomicAdd(&cursor[r], 1);
            adj[pos] = c;
        }
    }
}

__global__ __launch_bounds__(256) void k_gather_csr(const float* __restrict__ x,
                                                    const int* __restrict__ adj,
                                                    const int* __restrict__ offs,
                                                    const int* __restrict__ deg,
                                                    float* __restrict__ out, int n) {
    int lane = threadIdx.x & 63;
    int rowi = blockIdx.x * 4 + (threadIdx.x >> 6);
    if (rowi >= n) return;

    const float2* __restrict__ x2 = (const float2*)x;
    int beg = offs[rowi];
    int cnt = deg[rowi] - 1;

    float2 acc = make_float2(0.0f, 0.0f);
    for (int base = 0; base < cnt; base += 64) {
        int m = cnt - base; if (m > 64) m = 64;
        int a = 0;
        if (lane < m) a = adj[beg + base + lane];
        for (int nb = 0; nb < m; ++nb) {
            int c = __shfl(a, nb);
            float w = rsqrtf((float)deg[c]);
            float2 v = x2[c * (DFEAT / 2) + lane];
            acc.x += w * v.x;
            acc.y += w * v.y;
        }
    }
    float di = rsqrtf((float)deg[rowi]);
    float2 self = x2[rowi * (DFEAT / 2) + lane];
    acc.x = di * (acc.x + di * self.x);
    acc.y = di * (acc.y + di * self.y);

    float nsq = acc.x * acc.x + acc.y * acc.y;
    #pragma unroll
    for (int off = 32; off > 0; off >>= 1) nsq += __shfl_xor(nsq, off);

    float un = fmaxf(sqrtf(nsq), 1e-15f);
    float th = tanhf(un);
    float scale = th / un;
    if (th > MAXNORM) scale *= MAXNORM / th;

    float2 o = make_float2(acc.x * scale, acc.y * scale);
    ((float2*)out)[rowi * (DFEAT / 2) + lane] = o;
}

// ==================== launcher ====================

extern "C" void kernel_launch(void* const* d_in, const int* in_sizes, int n_in,
                              void* d_out, int out_size, void* d_ws, size_t ws_size,
                              hipStream_t stream) {
    const float* x          = (const float*)d_in[0];
    const int*   edge_index = (const int*)d_in[1];
    const int*   row = edge_index;            // [E]
    const int*   col = edge_index + N_EDGES;  // [E]
    float* out = (float*)d_out;
    char*  ws  = (char*)d_ws;

    size_t sz_xb  = sizeof(unsigned short) * (size_t)(N_NODES + 1) * DFEAT;  // +1 sentinel row
    size_t sz_adj = sizeof(int) * (size_t)N_NODES * CAP;
    size_t sz_deg = sizeof(int) * (size_t)N_NODES;
    size_t need_bf  = sz_xb + sz_adj + sz_deg + sizeof(int) * (1 + 2 * (size_t)OVF_CAP);
    size_t need_pad = sz_adj + sz_deg + sizeof(int) * (1 + 2 * (size_t)OVF_CAP);

    dim3 blk(256);
    if (ws_size >= need_bf) {
        size_t off = 0;
        unsigned int* xb = (unsigned int*)(ws + off); off += sz_xb;    // 16B-aligned
        int* adj     = (int*)(ws + off); off += sz_adj;
        int* deg     = (int*)(ws + off); off += sz_deg;
        int* ovf_cnt = (int*)(ws + off); off += sizeof(int);
        int* ovf     = (int*)(ws + off);

        int nprep = (N_NODES + 1) * (DFEAT / 8);   // 16 threads per row incl. sentinel
        k_zero<<<dim3((N_NODES + 255) / 256), blk, 0, stream>>>(deg, ovf_cnt, N_NODES);
        k_build<<<dim3((N_EDGES + 255) / 256), blk, 0, stream>>>(row, col, deg, adj, ovf, ovf_cnt, N_EDGES);
        k_prep<<<dim3((nprep + 255) / 256), blk, 0, stream>>>(x, deg, xb, nprep);
        k_gather_bf<<<dim3((N_NODES + 3) / 4), blk, 0, stream>>>(xb, adj, deg, ovf, ovf_cnt, out, N_NODES);
    } else if (ws_size >= need_pad) {
        size_t off = 0;
        int* adj     = (int*)(ws + off); off += sz_adj;
        int* deg     = (int*)(ws + off); off += sz_deg;
        int* ovf_cnt = (int*)(ws + off); off += sizeof(int);
        int* ovf     = (int*)(ws + off);

        k_zero<<<dim3((N_NODES + 255) / 256), blk, 0, stream>>>(deg, ovf_cnt, N_NODES);
        k_build<<<dim3((N_EDGES + 255) / 256), blk, 0, stream>>>(row, col, deg, adj, ovf, ovf_cnt, N_EDGES);
        k_gather_pad<<<dim3((N_NODES + 3) / 4), blk, 0, stream>>>(x, adj, deg, ovf, ovf_cnt, out, N_NODES);
    } else {
        size_t off = 0;
        int* deg       = (int*)(ws + off); off += sizeof(int) * (size_t)N_NODES;
        int* offs      = (int*)(ws + off); off += sizeof(int) * (size_t)N_NODES;
        int* cursor    = (int*)(ws + off); off += sizeof(int) * (size_t)N_NODES;
        int* blockSums = (int*)(ws + off); off += sizeof(int) * (size_t)NUM_SCAN_BLOCKS;
        int* blockBase = (int*)(ws + off); off += sizeof(int) * (size_t)NUM_SCAN_BLOCKS;
        int* adj       = (int*)(ws + off);

        k_init_deg<<<dim3((N_NODES + 255) / 256), blk, 0, stream>>>(deg, N_NODES);
        k_hist<<<dim3((N_EDGES + 255) / 256), blk, 0, stream>>>(row, col, deg, N_EDGES);
        k_block_sums<<<dim3(NUM_SCAN_BLOCKS), dim3(SCAN_BLK), 0, stream>>>(deg, blockSums, N_NODES);
        k_scan_blocks<<<dim3(1), dim3(SCAN_BLK), 0, stream>>>(blockSums, blockBase);
        k_block_scan<<<dim3(NUM_SCAN_BLOCKS), dim3(SCAN_BLK), 0, stream>>>(deg, blockBase, offs, cursor, N_NODES);
        k_scatter<<<dim3((N_EDGES + 255) / 256), blk, 0, stream>>>(row, col, cursor, adj, N_EDGES);
        k_gather_csr<<<dim3((N_NODES + 3) / 4), blk, 0, stream>>>(x, adj, offs, deg, out, N_NODES);
    }
}